// Round 2
// baseline (375.858 us; speedup 1.0000x reference)
//
#include <hip/hip_runtime.h>
#include <hip/hip_bf16.h>

// Problem: HMM forward algorithm in log space (fp32 in / fp32 out).
// B=64 batch, D=128 steps, A=128 states.
// Key insight: reference's [A,A] matrix scan has identical rows -> collapses
// to a per-b vector recursion v_{t+1}[j] = lse_k(v[k]+logT[t,k,j]) + bern.
// exp-trick: precompute E[t][j][k] = exp(u - Z[t,k] - c[t,j]) in fp32 ws,
// main loop is then a pure-FMA log-matvec per step.

#define B_ 64
#define D_ 128
#define A_ 128
#define T_ 127 // D-1

// workspace layout (float offsets). total = 2146176 floats = 8.59 MB
#define E_OFF 0
#define E_SZ (T_ * A_ * A_)        // 2080768: E transposed [t][j][k]
#define SC_OFF (E_OFF + E_SZ)      // float4 per (t,j): {c[t,j], g0[t+1,j], g1[t+1,j], pad}
#define SC_SZ (T_ * A_ * 4)        // 65024
#define GI_OFF (SC_OFF + SC_SZ)    // float2 per j: {g0[0,j], g1[0,j]}
#define GI_SZ (A_ * 2)
#define LP_OFF (GI_OFF + GI_SZ)    // log_p_a1[j] fp32
#define LP_SZ (A_)

__device__ __forceinline__ float rdlane(float v, int lane) {
    return __int_as_float(__builtin_amdgcn_readlane(__float_as_int(v), lane));
}

// ---------------- prep kernel: Z, c, E (one block per t) ----------------
// u[t] tile is 64KB fp32 -> too big for static LDS; read global directly,
// phases 2/3 hit L1/L2. Prep is off the critical path (127 parallel blocks).
__global__ __launch_bounds__(256) void prep_E(const float* __restrict__ uT,
                                              float* __restrict__ ws) {
    __shared__ float Zl[A_];
    __shared__ float cl[A_];
    const int t = blockIdx.x, tid = threadIdx.x;
    const float* u = uT + (size_t)t * A_ * A_;

    // Z[k] = lse_j u[k][j]
    if (tid < A_) {
        int k = tid;
        const float* row = u + k * A_;
        float m = -1e30f;
        for (int j = 0; j < A_; j++) m = fmaxf(m, row[j]);
        float s = 0.f;
        for (int j = 0; j < A_; j++) s += __expf(row[j] - m);
        Zl[k] = m + __logf(s);
    }
    __syncthreads();

    // c[j] = max_k (u[k][j] - Z[k]);  also write SC.x
    if (tid < A_) {
        int j = tid;
        float m = -1e30f;
        for (int k = 0; k < A_; k++) m = fmaxf(m, u[k * A_ + j] - Zl[k]);
        cl[j] = m;
        ws[SC_OFF + ((size_t)t * A_ + j) * 4 + 0] = m;
    }
    __syncthreads();

    // E[t][j][k] = exp(u[k][j] - Z[k] - c[j]), k-contiguous (transposed) store
    float* E = ws + E_OFF + (size_t)t * A_ * A_;
    for (int jj = 0; jj < 64; jj++) {
        int j = 2 * jj + (tid >> 7);
        int k = tid & 127;
        E[j * A_ + k] = __expf(u[k * A_ + j] - Zl[k] - cl[j]);
    }
}

// ---------------- prep kernel: log_p_a1 (also writes output 1) ----------------
__global__ void prep_p1(const float* __restrict__ u1,
                        float* __restrict__ ws, float* __restrict__ out) {
    __shared__ float tmp[A_];
    __shared__ float lse_s;
    int j = threadIdx.x;
    float v = u1[j];
    tmp[j] = v;
    __syncthreads();
    if (j == 0) {
        float m = -1e30f;
        for (int i = 0; i < A_; i++) m = fmaxf(m, tmp[i]);
        float s = 0.f;
        for (int i = 0; i < A_; i++) s += __expf(tmp[i] - m);
        lse_s = m + __logf(s);
    }
    __syncthreads();
    float lp = v - lse_s;
    ws[LP_OFF + j] = lp;
    out[B_ * A_ + j] = lp;
}

// ---------------- prep kernel: Bernoulli terms g0/g1 ----------------
__global__ void prep_g(const float* __restrict__ l,
                       float* __restrict__ ws) {
    int d = blockIdx.x, j = threadIdx.x;
    float lv = l[d * A_ + j];
    // softplus, stable
    float sp = (lv > 0.f) ? (lv + log1pf(__expf(-lv))) : log1pf(__expf(lv));
    float g0 = -sp;        // x == 0
    float g1 = lv - sp;    // x == 1
    if (d == 0) {
        ws[GI_OFF + 2 * j] = g0;
        ws[GI_OFF + 2 * j + 1] = g1;
    } else {
        ws[SC_OFF + ((size_t)(d - 1) * A_ + j) * 4 + 1] = g0;
        ws[SC_OFF + ((size_t)(d - 1) * A_ + j) * 4 + 2] = g1;
    }
}

// ---------------- main kernel: 64 blocks (one per b) x 256 threads ----------------
// wave w owns k in [32w,32w+32); lane l holds v[2l], v[2l+1] (full v per wave,
// redundant across waves -> ew via readlane, no LDS broadcast, 1 barrier/step).
__global__ __launch_bounds__(256, 1) void fwd(const float* __restrict__ x,
                                              const float* __restrict__ ws,
                                              float* __restrict__ out) {
    __shared__ float part[2][4][A_]; // double-buffered cross-wave partials
    const int b = blockIdx.x, tid = threadIdx.x;
    const int wave = tid >> 6, lane = tid & 63;
    const int j0 = 2 * lane, j1 = j0 + 1;
    const int kbase = 32 * wave;   // this wave's k-group
    const int lbase = 16 * wave;   // lanes holding ew for this k-group

    const float* E = ws + E_OFF;
    const float4* SC = (const float4*)(ws + SC_OFF);
    const float4* GI4 = (const float4*)(ws + GI_OFF);
    const float* LP = ws + LP_OFF;
    const float* xr = x + b * D_;

    // ---- init: v0[j] = logp1[j] + bern(b,0,j)
    float xv0 = xr[0];
    float4 g = GI4[lane]; // (g0_j0, g1_j0, g0_j1, g1_j1)
    float2 lp = *(const float2*)(LP + j0);
    float v0 = lp.x + (xv0 != 0.f ? g.y : g.x);
    float v1 = lp.y + (xv0 != 0.f ? g.w : g.z);
    float m = rdlane(v0, 0); // normalizer: v[0]; spread bound ~14 => exp safe

    // double-buffered prefetch registers
    float4 ea0[8], ea1[8], eb0[8], eb1[8];
    float4 scA0, scA1, scB0, scB1;
    float xA, xB;
    {
        const float4* p0 = (const float4*)(E + (size_t)0 * A_ * A_ + j0 * A_ + kbase);
        const float4* p1 = (const float4*)(E + (size_t)0 * A_ * A_ + j1 * A_ + kbase);
#pragma unroll
        for (int i = 0; i < 8; i++) { ea0[i] = p0[i]; ea1[i] = p1[i]; }
        scA0 = SC[0 * A_ + j0];
        scA1 = SC[0 * A_ + j1];
        xA = xr[1];
    }
    xB = 0.f; scB0 = scA0; scB1 = scA1; // silence maybe-uninitialized paths

#define STEP(T, CE0, CE1, CS0, CS1, CX, NE0, NE1, NS0, NS1, NX, DO_PF)              \
    {                                                                               \
        if (DO_PF) { /* prefetch step T+1 (E addrs depend only on t) */             \
            const float4* q0 = (const float4*)(E + (size_t)((T) + 1) * A_ * A_ +    \
                                               j0 * A_ + kbase);                    \
            const float4* q1 = (const float4*)(E + (size_t)((T) + 1) * A_ * A_ +    \
                                               j1 * A_ + kbase);                    \
            _Pragma("unroll") for (int i = 0; i < 8; i++) {                         \
                NE0[i] = q0[i];                                                     \
                NE1[i] = q1[i];                                                     \
            }                                                                       \
            NS0 = SC[((T) + 1) * A_ + j0];                                          \
            NS1 = SC[((T) + 1) * A_ + j1];                                          \
            NX = xr[(T) + 2];                                                       \
        }                                                                           \
        float ew0 = __expf(v0 - m), ew1 = __expf(v1 - m);                           \
        float p0a = 0.f, p0b = 0.f, p1a = 0.f, p1b = 0.f;                           \
        _Pragma("unroll") for (int i = 0; i < 8; i++) {                             \
            float sa0 = rdlane(ew0, lbase + 2 * i);     /* ew[kbase+4i]   */        \
            float sb0 = rdlane(ew1, lbase + 2 * i);     /* ew[kbase+4i+1] */        \
            float sa1 = rdlane(ew0, lbase + 2 * i + 1); /* ew[kbase+4i+2] */        \
            float sb1 = rdlane(ew1, lbase + 2 * i + 1); /* ew[kbase+4i+3] */        \
            p0a += sa0 * CE0[i].x; p0b += sb0 * CE0[i].y;                           \
            p0a += sa1 * CE0[i].z; p0b += sb1 * CE0[i].w;                           \
            p1a += sa0 * CE1[i].x; p1b += sb0 * CE1[i].y;                           \
            p1a += sa1 * CE1[i].z; p1b += sb1 * CE1[i].w;                           \
        }                                                                           \
        *(float2*)&part[(T) & 1][wave][j0] = make_float2(p0a + p0b, p1a + p1b);     \
        __syncthreads();                                                            \
        float a00 = part[(T) & 1][0][j0] + part[(T) & 1][1][j0];                    \
        float a01 = part[(T) & 1][2][j0] + part[(T) & 1][3][j0];                    \
        float a10 = part[(T) & 1][0][j1] + part[(T) & 1][1][j1];                    \
        float a11 = part[(T) & 1][2][j1] + part[(T) & 1][3][j1];                    \
        float acc0 = a00 + a01, acc1 = a10 + a11;                                   \
        v0 = __logf(acc0) + m + CS0.x + (CX != 0.f ? CS0.z : CS0.y);                \
        v1 = __logf(acc1) + m + CS1.x + (CX != 0.f ? CS1.z : CS1.y);                \
        m = rdlane(v0, 0);                                                          \
    }

    for (int t = 0; t < 126; t += 2) {
        STEP(t, ea0, ea1, scA0, scA1, xA, eb0, eb1, scB0, scB1, xB, true)
        STEP(t + 1, eb0, eb1, scB0, scB1, xB, ea0, ea1, scA0, scA1, xA, true)
    }
    STEP(126, ea0, ea1, scA0, scA1, xA, eb0, eb1, scB0, scB1, xB, false)
#undef STEP

    // final: L_b = lse_j v[j]; in-wave butterfly (each wave has full v)
    float loc = __expf(v0 - m) + __expf(v1 - m);
#pragma unroll
    for (int off = 1; off < 64; off <<= 1) loc += __shfl_xor(loc, off, 64);
    float L = m + __logf(loc);
    if (wave == 0) {
        out[b * A_ + j0] = L;
        out[b * A_ + j1] = L;
    }
}

extern "C" void kernel_launch(void* const* d_in, const int* in_sizes, int n_in,
                              void* d_out, int out_size, void* d_ws, size_t ws_size,
                              hipStream_t stream) {
    const float* x = (const float*)d_in[0];   // [B,D]
    const float* u1 = (const float*)d_in[1];  // [1,1,1,A]
    const float* uT = (const float*)d_in[2];  // [D-1,A,A]
    const float* l = (const float*)d_in[3];   // [1,D,1,A]
    float* ws = (float*)d_ws; // needs 8.59 MB
    float* out = (float*)d_out;

    hipLaunchKernelGGL(prep_E, dim3(T_), dim3(256), 0, stream, uT, ws);
    hipLaunchKernelGGL(prep_p1, dim3(1), dim3(A_), 0, stream, u1, ws, out);
    hipLaunchKernelGGL(prep_g, dim3(D_), dim3(A_), 0, stream, l, ws);
    hipLaunchKernelGGL(fwd, dim3(B_), dim3(256), 0, stream, x, ws, out);
}

// Round 4
// 274.777 us; speedup vs baseline: 1.3679x; 1.3679x over previous
//
#include <hip/hip_runtime.h>

// HMM forward algorithm, log space. B=64 chains, D=128 steps, A=128 states.
// v_{t+1}[j] = log(sum_k exp(v[k]-m) * E[t][j][k]) + m + BC[b][t][j]
// E[t][j][k] = exp(u[t][k][j] - Z[t][k]) stored fp16, pair-packed (k, k+64).
// fwd: ONE WAVE per chain, zero LDS, zero barriers. E prefetched 2 steps
// ahead into rotating VGPR buffers (512-VGPR budget at 1 wave/SIMD);
// compiler's per-register vmcnt tracking = fine-grained async pipeline.

#define B_ 64
#define D_ 128
#define A_ 128
#define T_ 127

// ws layout (4-byte units), total ~8.33 MB
#define E16_UINTS (T_ * 8192)            // [t][j][i]: uint = (E[j][i], E[j][i+64]) fp16
#define BC_OFF E16_UINTS                 // [b][t][pair] fp32 Bernoulli terms
#define BC_SZ (B_ * T_ * A_)
#define LP_OFF (BC_OFF + BC_SZ)          // log_p_a1 paired: [2l]=lp[l], [2l+1]=lp[l+64]

typedef _Float16 h2 __attribute__((ext_vector_type(2)));

__device__ __forceinline__ int packrtz(float a, float b) {
    auto p = __builtin_amdgcn_cvt_pkrtz(a, b); // low=a, high=b
    return __builtin_bit_cast(int, p);
}

__device__ __forceinline__ float dot2acc(unsigned int e, int s, float acc) {
#if __has_builtin(__builtin_amdgcn_fdot2)
    return __builtin_amdgcn_fdot2(__builtin_bit_cast(h2, e),
                                  __builtin_bit_cast(h2, s), acc, false);
#else
    h2 ev = __builtin_bit_cast(h2, e), sv = __builtin_bit_cast(h2, s);
    return acc + (float)ev.x * (float)sv.x + (float)ev.y * (float)sv.y;
#endif
}

template <int CTRL>
__device__ __forceinline__ float dpp_mov_self(float x) { // invalid lanes -> x
    return __int_as_float(__builtin_amdgcn_update_dpp(
        __float_as_int(x), __float_as_int(x), CTRL, 0xF, 0xF, false));
}
template <int CTRL>
__device__ __forceinline__ float dpp_mov_zero(float x) { // invalid lanes -> 0
    return __int_as_float(__builtin_amdgcn_update_dpp(
        0, __float_as_int(x), CTRL, 0xF, 0xF, true));
}
__device__ __forceinline__ float wave_max_bcast(float x) {
    x = fmaxf(x, dpp_mov_self<0x111>(x)); // row_shr1
    x = fmaxf(x, dpp_mov_self<0x112>(x)); // row_shr2
    x = fmaxf(x, dpp_mov_self<0x114>(x)); // row_shr4
    x = fmaxf(x, dpp_mov_self<0x118>(x)); // row_shr8
    x = fmaxf(x, dpp_mov_self<0x142>(x)); // bcast15
    x = fmaxf(x, dpp_mov_self<0x143>(x)); // bcast31
    return __int_as_float(__builtin_amdgcn_readlane(__float_as_int(x), 63));
}
__device__ __forceinline__ float wave_sum_bcast(float x) {
    x += dpp_mov_zero<0x111>(x);
    x += dpp_mov_zero<0x112>(x);
    x += dpp_mov_zero<0x114>(x);
    x += dpp_mov_zero<0x118>(x);
    x += dpp_mov_zero<0x142>(x);
    x += dpp_mov_zero<0x143>(x);
    return __int_as_float(__builtin_amdgcn_readlane(__float_as_int(x), 63));
}

// ---------------- prep: Z[t][k] = lse_j u[t][k][j]; E16[t][j][i] pair-packed ----------------
__global__ __launch_bounds__(256) void prep_E(const float* __restrict__ uT,
                                              unsigned int* __restrict__ wsu) {
    __shared__ float Zl[A_];
    const int t = blockIdx.x, tid = threadIdx.x;
    const int wave = tid >> 6, lane = tid & 63;
    const float* u = uT + (size_t)t * A_ * A_;

    for (int rr = 0; rr < 32; rr++) {
        int r = wave * 32 + rr;
        float a = u[r * A_ + lane];
        float c = u[r * A_ + lane + 64];
        float mx = wave_max_bcast(fmaxf(a, c));
        float s = wave_sum_bcast(__expf(a - mx) + __expf(c - mx));
        if (lane == 0) Zl[r] = mx + __logf(s);
    }
    __syncthreads();

    unsigned int* Et = wsu + (size_t)t * 8192;
    for (int it = 0; it < 32; it++) {
        int idx = it * 256 + tid;   // 0..8191
        int j = idx >> 6, i = idx & 63;
        float e0 = __expf(u[i * A_ + j] - Zl[i]);
        float e1 = __expf(u[(i + 64) * A_ + j] - Zl[i + 64]);
        Et[idx] = (unsigned int)packrtz(e0, e1);
    }
}

// ---------------- prep: log_p_a1 -> LP (paired) + output 1 ----------------
__global__ void prep_p1(const float* __restrict__ u1,
                        float* __restrict__ ws, float* __restrict__ out) {
    __shared__ float tmp[A_];
    __shared__ float lse_s;
    int j = threadIdx.x;
    float v = u1[j];
    tmp[j] = v;
    __syncthreads();
    if (j == 0) {
        float mm = -1e30f;
        for (int i = 0; i < A_; i++) mm = fmaxf(mm, tmp[i]);
        float s = 0.f;
        for (int i = 0; i < A_; i++) s += __expf(tmp[i] - mm);
        lse_s = mm + __logf(s);
    }
    __syncthreads();
    float lp = v - lse_s;
    int pi = (j < 64) ? (2 * j) : (2 * (j - 64) + 1);
    ws[LP_OFF + pi] = lp;
    out[B_ * A_ + j] = lp;
}

// ---------------- prep: BC[b][t][pair] = bern(x[b][t+1], state), paired ----------------
__global__ void prep_bc(const float* __restrict__ x, const float* __restrict__ lg,
                        float* __restrict__ ws) {
    const int t = blockIdx.x, j = threadIdx.x;
    float lv = lg[(t + 1) * A_ + j];
    float sp = (lv > 0.f) ? (lv + log1pf(__expf(-lv))) : log1pf(__expf(lv));
    float g0 = -sp, g1 = lv - sp;
    int pi = (j < 64) ? (2 * j) : (2 * (j - 64) + 1);
    float* BC = ws + BC_OFF;
    for (int b = 0; b < B_; b++) {
        float xv = x[b * D_ + t + 1];
        BC[((size_t)b * T_ + t) * A_ + pi] = (xv != 0.f) ? g1 : g0;
    }
}

// ---------------- main: 64 blocks x 1 wave, register-pipelined ----------------
#define LOADSTEP(E0, E1, BC, TT)                                              \
    {                                                                         \
        const uint4* p0 = e0p + (TT) * 2048;                                  \
        const uint4* p1 = e1p + (TT) * 2048;                                  \
        _Pragma("unroll") for (int i2 = 0; i2 < 16; i2++) {                   \
            E0[i2] = p0[i2];                                                  \
            E1[i2] = p1[i2];                                                  \
        }                                                                     \
        BC = bcbase[(TT) * 64 + lane];                                        \
    }

#define COMPUTE(E0, E1, BC)                                                   \
    {                                                                         \
        float a00 = 0, a01 = 0, a02 = 0, a03 = 0;                             \
        float a10 = 0, a11 = 0, a12 = 0, a13 = 0;                             \
        _Pragma("unroll") for (int c = 0; c < 16; c++) {                      \
            int s0 = __builtin_amdgcn_readlane(ewi, 4 * c + 0);               \
            int s1 = __builtin_amdgcn_readlane(ewi, 4 * c + 1);               \
            int s2 = __builtin_amdgcn_readlane(ewi, 4 * c + 2);               \
            int s3 = __builtin_amdgcn_readlane(ewi, 4 * c + 3);               \
            a00 = dot2acc(E0[c].x, s0, a00);                                  \
            a01 = dot2acc(E0[c].y, s1, a01);                                  \
            a02 = dot2acc(E0[c].z, s2, a02);                                  \
            a03 = dot2acc(E0[c].w, s3, a03);                                  \
            a10 = dot2acc(E1[c].x, s0, a10);                                  \
            a11 = dot2acc(E1[c].y, s1, a11);                                  \
            a12 = dot2acc(E1[c].z, s2, a12);                                  \
            a13 = dot2acc(E1[c].w, s3, a13);                                  \
        }                                                                     \
        float acc0 = (a00 + a01) + (a02 + a03);                               \
        float acc1 = (a10 + a11) + (a12 + a13);                               \
        v0 = __logf(acc0) + m + BC.x;                                         \
        v1 = __logf(acc1) + m + BC.y;                                         \
        m = wave_max_bcast(fmaxf(v0, v1));                                    \
        ewi = packrtz(__expf(v0 - m), __expf(v1 - m));                        \
    }

__global__ __launch_bounds__(64, 1) void fwd(const float* __restrict__ x,
                                             const float* __restrict__ lg,
                                             const float* __restrict__ ws,
                                             float* __restrict__ out) {
    const int b = blockIdx.x, lane = threadIdx.x;
    const unsigned int* E16 = (const unsigned int*)ws;
    const float* LP = ws + LP_OFF;

    // init: v0 = lp[lane] + bern(x[b][0], lane); v1 for state lane+64
    float ll0 = lg[lane], ll1 = lg[lane + 64];
    float sp0 = (ll0 > 0.f) ? (ll0 + log1pf(__expf(-ll0))) : log1pf(__expf(ll0));
    float sp1 = (ll1 > 0.f) ? (ll1 + log1pf(__expf(-ll1))) : log1pf(__expf(ll1));
    float xv0 = x[b * D_];
    float2 lp2 = *(const float2*)&LP[2 * lane];
    float v0 = lp2.x + ((xv0 != 0.f) ? (ll0 - sp0) : (-sp0));
    float v1 = lp2.y + ((xv0 != 0.f) ? (ll1 - sp1) : (-sp1));
    float m = wave_max_bcast(fmaxf(v0, v1));
    int ewi = packrtz(__expf(v0 - m), __expf(v1 - m));

    const uint4* e0p = (const uint4*)E16 + (size_t)lane * 16;        // row j=lane
    const uint4* e1p = (const uint4*)E16 + (size_t)(lane + 64) * 16; // row j=lane+64
    const float2* bcbase = (const float2*)(ws + BC_OFF + (size_t)b * T_ * A_);

    uint4 EA0[16], EA1[16], EB0[16], EB1[16];
    float2 bcA, bcB;
    LOADSTEP(EA0, EA1, bcA, 0)
    LOADSTEP(EB0, EB1, bcB, 1)

    for (int t = 0; t < 124; t += 2) {   // steps 0..123, prefetch up to 125
        COMPUTE(EA0, EA1, bcA)
        LOADSTEP(EA0, EA1, bcA, t + 2)
        COMPUTE(EB0, EB1, bcB)
        LOADSTEP(EB0, EB1, bcB, t + 3)
    }
    COMPUTE(EA0, EA1, bcA)               // step 124
    LOADSTEP(EA0, EA1, bcA, 126)
    COMPUTE(EB0, EB1, bcB)               // step 125
    COMPUTE(EA0, EA1, bcA)               // step 126

    float s = __expf(v0 - m) + __expf(v1 - m);
    s = wave_sum_bcast(s);
    float L = m + __logf(s);
    out[b * A_ + lane] = L;
    out[b * A_ + lane + 64] = L;
}

extern "C" void kernel_launch(void* const* d_in, const int* in_sizes, int n_in,
                              void* d_out, int out_size, void* d_ws, size_t ws_size,
                              hipStream_t stream) {
    const float* x = (const float*)d_in[0];    // [B,D]
    const float* u1 = (const float*)d_in[1];   // [1,1,1,A]
    const float* uT = (const float*)d_in[2];   // [D-1,A,A]
    const float* lg = (const float*)d_in[3];   // [1,D,1,A]
    float* ws = (float*)d_ws;                  // ~8.33 MB
    float* out = (float*)d_out;

    prep_E<<<dim3(T_), dim3(256), 0, stream>>>(uT, (unsigned int*)ws);
    prep_p1<<<dim3(1), dim3(A_), 0, stream>>>(u1, ws, out);
    prep_bc<<<dim3(T_), dim3(A_), 0, stream>>>(x, lg, ws);
    fwd<<<dim3(B_), dim3(64), 0, stream>>>(x, lg, ws, out);
}

// Round 5
// 163.707 us; speedup vs baseline: 2.2959x; 1.6785x over previous
//
#include <hip/hip_runtime.h>

// HMM forward, log space. B=64 chains, D=128 steps, A=128 states.
// v_{t+1}[j] = log(sum_k exp(v[k]-m)*E[t][j][k]) + m + BC[b][t][j]
// E[t][j][k] = exp(u[t][k][j] - Z[t][k]) fp16, k-pairs (2i,2i+1).
// fwd: 64 blocks x 4 waves; wave w owns j in [32w,32w+32); lanes split k in
// halves. Cross-wave exchange of exp(v - wavemax) via LDS + RAW s_barrier
// (lgkmcnt-only drain -> global prefetch loads stay in flight across it).
// E prefetched 2 steps ahead into a 3-buffer VGPR rotation (96 VGPRs).

#define B_ 64
#define D_ 128
#define A_ 128
#define T_ 127

// ws layout (4-byte units), ~8.32 MB
#define E16_UINTS (T_ * 8192)      // [t][q][h][w][jl][c] uints, see addr formula
#define BC_OFF E16_UINTS           // [b][t][j] fp32
#define BC_SZ (B_ * T_ * A_)
#define LP_OFF (BC_OFF + BC_SZ)    // log_p_a1[j] fp32

typedef _Float16 h2 __attribute__((ext_vector_type(2)));

__device__ __forceinline__ int packrtz(float a, float b) {
    auto p = __builtin_amdgcn_cvt_pkrtz(a, b); // low=a, high=b
    return __builtin_bit_cast(int, p);
}
__device__ __forceinline__ float dot2acc(unsigned int e, unsigned int s, float acc) {
    return __builtin_amdgcn_fdot2(__builtin_bit_cast(h2, e),
                                  __builtin_bit_cast(h2, s), acc, false);
}

template <int CTRL>
__device__ __forceinline__ float dpp_mov_self(float x) {
    return __int_as_float(__builtin_amdgcn_update_dpp(
        __float_as_int(x), __float_as_int(x), CTRL, 0xF, 0xF, false));
}
template <int CTRL>
__device__ __forceinline__ float dpp_mov_zero(float x) {
    return __int_as_float(__builtin_amdgcn_update_dpp(
        0, __float_as_int(x), CTRL, 0xF, 0xF, true));
}
__device__ __forceinline__ float wave_max_bcast(float x) {
    x = fmaxf(x, dpp_mov_self<0x111>(x));
    x = fmaxf(x, dpp_mov_self<0x112>(x));
    x = fmaxf(x, dpp_mov_self<0x114>(x));
    x = fmaxf(x, dpp_mov_self<0x118>(x));
    x = fmaxf(x, dpp_mov_self<0x142>(x));
    x = fmaxf(x, dpp_mov_self<0x143>(x));
    return __int_as_float(__builtin_amdgcn_readlane(__float_as_int(x), 63));
}
__device__ __forceinline__ float wave_sum_bcast(float x) {
    x += dpp_mov_zero<0x111>(x);
    x += dpp_mov_zero<0x112>(x);
    x += dpp_mov_zero<0x114>(x);
    x += dpp_mov_zero<0x118>(x);
    x += dpp_mov_zero<0x142>(x);
    x += dpp_mov_zero<0x143>(x);
    return __int_as_float(__builtin_amdgcn_readlane(__float_as_int(x), 63));
}

// ---------------- single merged prep kernel: 127 blocks x 256 ----------------
__global__ __launch_bounds__(256) void prep(const float* __restrict__ uT,
                                            const float* __restrict__ u1,
                                            const float* __restrict__ x,
                                            const float* __restrict__ lg,
                                            float* __restrict__ ws,
                                            float* __restrict__ out) {
    __shared__ float Zl[A_];
    const int t = blockIdx.x, tid = threadIdx.x;
    const int wave = tid >> 6, lane = tid & 63;
    const float* u = uT + (size_t)t * A_ * A_;

    // Z[k] = lse_j u[k][j], wave-parallel per row
    for (int rr = 0; rr < 32; rr++) {
        int r = wave * 32 + rr;
        float a = u[r * A_ + lane];
        float c = u[r * A_ + lane + 64];
        float mx = wave_max_bcast(fmaxf(a, c));
        float s = wave_sum_bcast(__expf(a - mx) + __expf(c - mx));
        if (lane == 0) Zl[r] = mx + __logf(s);
    }
    __syncthreads();

    // E16 store, coalesced in the fwd-consumption layout:
    // addr_u(t,q,h,w,jl,c) = t*8192 + q*1024 + h*512 + w*128 + jl*4 + c
    // uint = pack(e(2i,j), e(2i+1,j)), i = 32h+4q+c, j = 32w+jl
    unsigned int* Et = (unsigned int*)ws + (size_t)t * 8192;
    for (int it = 0; it < 32; it++) {
        int a = it * 256 + tid;     // 0..8191
        int c = a & 3, jl = (a >> 2) & 31, w = (a >> 7) & 3;
        int h = (a >> 9) & 1, q = (a >> 10) & 7;
        int j = 32 * w + jl;
        int i = 32 * h + 4 * q + c;
        float e0 = __expf(u[(2 * i) * A_ + j] - Zl[2 * i]);
        float e1 = __expf(u[(2 * i + 1) * A_ + j] - Zl[2 * i + 1]);
        Et[a] = (unsigned int)packrtz(e0, e1);
    }

    // BC[b][t][j] = bern(x[b][t+1], j)
    {
        int j = tid & 127, hb = tid >> 7;
        float lv = lg[(t + 1) * A_ + j];
        float sp = (lv > 0.f) ? (lv + log1pf(__expf(-lv))) : log1pf(__expf(lv));
        float g0 = -sp, g1 = lv - sp;
        float* BC = ws + BC_OFF;
        for (int b = hb * 32; b < hb * 32 + 32; b++) {
            float xv = x[b * D_ + t + 1];
            BC[((size_t)b * T_ + t) * A_ + j] = (xv != 0.f) ? g1 : g0;
        }
    }

    // block 0, wave 0: log_softmax(u1) -> LP + output 1
    if (t == 0 && wave == 0) {
        float a = u1[lane], c = u1[lane + 64];
        float mx = wave_max_bcast(fmaxf(a, c));
        float s = wave_sum_bcast(__expf(a - mx) + __expf(c - mx));
        float lse = mx + __logf(s);
        ws[LP_OFF + lane] = a - lse;
        ws[LP_OFF + lane + 64] = c - lse;
        out[B_ * A_ + lane] = a - lse;
        out[B_ * A_ + lane + 64] = c - lse;
    }
}

// ---------------- main: 64 blocks x 256 (4 waves), raw barriers ----------------
// RAW barrier: lgkmcnt drain only (LDS visibility); vmcnt loads stay in flight.
#define BARRIER() asm volatile("s_waitcnt lgkmcnt(0)\n\ts_barrier" ::: "memory")

#define STEP(T, EC, EP, BCC, BCP, DOPF)                                       \
    {                                                                         \
        const int p = (T) & 1, np = p ^ 1;                                    \
        if (DOPF) { /* prefetch step T+2 into free buffer EP */               \
            const uint4* pf = (const uint4*)(Eb + (size_t)((T) + 2) * 32768); \
            _Pragma("unroll") for (int q = 0; q < 8; q++) EP[q] = pf[q];      \
            BCP = BCg[((T) + 2) * A_];                                        \
        }                                                                     \
        float4 vm4 = *(const float4*)&vmaxl[p][0];                            \
        const uint4* ewp = (const uint4*)&ewl[p][0] + h * 8;                  \
        uint4 ew_[8];                                                         \
        _Pragma("unroll") for (int q = 0; q < 8; q++) ew_[q] = ewp[q];        \
        float vA = h ? vm4.z : vm4.x;                                         \
        float vB = h ? vm4.w : vm4.y;                                         \
        float m = fmaxf(fmaxf(vm4.x, vm4.y), fmaxf(vm4.z, vm4.w));            \
        float fA = __expf(vA - m), fB = __expf(vB - m);                       \
        float s0 = 0, s1 = 0, s2 = 0, s3 = 0;                                 \
        float r0 = 0, r1 = 0, r2 = 0, r3 = 0;                                 \
        _Pragma("unroll") for (int q = 0; q < 4; q++) {                       \
            s0 = dot2acc(EC[q].x, ew_[q].x, s0);                              \
            s1 = dot2acc(EC[q].y, ew_[q].y, s1);                              \
            s2 = dot2acc(EC[q].z, ew_[q].z, s2);                              \
            s3 = dot2acc(EC[q].w, ew_[q].w, s3);                              \
        }                                                                     \
        _Pragma("unroll") for (int q = 4; q < 8; q++) {                       \
            r0 = dot2acc(EC[q].x, ew_[q].x, r0);                              \
            r1 = dot2acc(EC[q].y, ew_[q].y, r1);                              \
            r2 = dot2acc(EC[q].z, ew_[q].z, r2);                              \
            r3 = dot2acc(EC[q].w, ew_[q].w, r3);                              \
        }                                                                     \
        float S = ((s0 + s1) + (s2 + s3)) * fA + ((r0 + r1) + (r2 + r3)) * fB;\
        S += __shfl_xor(S, 32, 64);                                           \
        float vnew = __logf(S) + m + BCC;                                     \
        float mw2 = wave_max_bcast(vnew);                                     \
        ewl[np][j] = (_Float16)__expf(vnew - mw2);                            \
        vmaxl[np][w] = mw2;                                                   \
        v = vnew;                                                             \
        BARRIER();                                                            \
    }

__global__ __launch_bounds__(256, 1) void fwd(const float* __restrict__ x,
                                              const float* __restrict__ lg,
                                              const float* __restrict__ ws,
                                              float* __restrict__ out) {
    __shared__ __align__(16) _Float16 ewl[2][A_];
    __shared__ __align__(16) float vmaxl[2][4];
    __shared__ float sums[4];
    const int b = blockIdx.x, tid = threadIdx.x;
    const int w = tid >> 6, lane = tid & 63;
    const int h = lane >> 5, jl = lane & 31;
    const int j = 32 * w + jl;

    const char* Eb = (const char*)ws + (size_t)h * 2048 + w * 512 + jl * 16;
    const float* BCg = ws + BC_OFF + (size_t)b * T_ * A_ + j; // + t*A_
    const float* LP = ws + LP_OFF;

    // init v_0[j] = log_p_a1[j] + bern(x[b][0], j)
    float ll = lg[j];
    float sp = (ll > 0.f) ? (ll + log1pf(__expf(-ll))) : log1pf(__expf(ll));
    float xv0 = x[b * D_];
    float v = LP[j] + ((xv0 != 0.f) ? (ll - sp) : (-sp));
    float mw = wave_max_bcast(v);
    ewl[0][j] = (_Float16)__expf(v - mw);
    vmaxl[0][w] = mw;

    uint4 E0[8], E1[8], E2[8];
    float bc0, bc1, bc2;
    {   // preload t=0 -> E0, t=1 -> E1 (E2 filled by step 0's prefetch)
        const uint4* p0 = (const uint4*)(Eb);
        const uint4* p1 = (const uint4*)(Eb + 32768);
#pragma unroll
        for (int q = 0; q < 8; q++) { E0[q] = p0[q]; E1[q] = p1[q]; }
        bc0 = BCg[0];
        bc1 = BCg[A_];
    }
    bc2 = 0.f;
    BARRIER();

    for (int t = 0; t < 123; t += 3) {  // steps 0..122
        STEP(t + 0, E0, E2, bc0, bc2, 1)
        STEP(t + 1, E1, E0, bc1, bc0, 1)
        STEP(t + 2, E2, E1, bc2, bc1, 1)
    }
    STEP(123, E0, E2, bc0, bc2, 1)  // pf 125 -> E2
    STEP(124, E1, E0, bc1, bc0, 1)  // pf 126 -> E0
    STEP(125, E2, E1, bc2, bc1, 0)
    STEP(126, E0, E1, bc0, bc1, 0)

    // final: L = lse_j v_127[j]
    float4 vmf = *(const float4*)&vmaxl[1][0];
    float mf = fmaxf(fmaxf(vmf.x, vmf.y), fmaxf(vmf.z, vmf.w));
    float sw = wave_sum_bcast(__expf(v - mf)) * 0.5f; // halves duplicate j
    sums[w] = sw;
    BARRIER();
    float tot = (sums[0] + sums[1]) + (sums[2] + sums[3]);
    float L = mf + __logf(tot);
    if (tid < A_) out[b * A_ + tid] = L;
}

extern "C" void kernel_launch(void* const* d_in, const int* in_sizes, int n_in,
                              void* d_out, int out_size, void* d_ws, size_t ws_size,
                              hipStream_t stream) {
    const float* x = (const float*)d_in[0];    // [B,D]
    const float* u1 = (const float*)d_in[1];   // [1,1,1,A]
    const float* uT = (const float*)d_in[2];   // [D-1,A,A]
    const float* lg = (const float*)d_in[3];   // [1,D,1,A]
    float* ws = (float*)d_ws;                  // ~8.32 MB
    float* out = (float*)d_out;

    prep<<<dim3(T_), dim3(256), 0, stream>>>(uT, u1, x, lg, ws, out);
    fwd<<<dim3(B_), dim3(256), 0, stream>>>(x, lg, ws, out);
}

// Round 6
// 158.637 us; speedup vs baseline: 2.3693x; 1.0320x over previous
//
#include <hip/hip_runtime.h>

// HMM forward, log space. B=64 chains, D=128 steps, A=128 states.
// v_{t+1}[j] = log(sum_k exp(v[k]-m)*E[t][j][k]) + m + BC[b][t][j]
// E[t][j][k] = exp(u[t][k][j] - Z[t][k]) fp16, k-pairs (2i,2i+1).
// fwd: 64 blocks x 4 waves; wave w owns j in [32w,32w+32); lanes split k in
// halves. Cross-wave exchange of exp(v - wavemax) via LDS + RAW s_barrier
// (lgkmcnt-only drain -> global prefetch loads stay in flight across it).
// E prefetched 2 steps ahead into a 3-buffer VGPR rotation; sched_barrier(0)
// after each prefetch batch pins the loads early (R5: compiler sank them,
// VGPR=64 -> exposed L2 latency every step).

#define B_ 64
#define D_ 128
#define A_ 128
#define T_ 127

// ws layout (4-byte units), ~8.32 MB
#define E16_UINTS (T_ * 8192)      // [t][q][h][w][jl][c] uints
#define BC_OFF E16_UINTS           // [b][t][j] fp32
#define BC_SZ (B_ * T_ * A_)
#define LP_OFF (BC_OFF + BC_SZ)    // log_p_a1[j] fp32

typedef _Float16 h2 __attribute__((ext_vector_type(2)));

__device__ __forceinline__ int packrtz(float a, float b) {
    auto p = __builtin_amdgcn_cvt_pkrtz(a, b); // low=a, high=b
    return __builtin_bit_cast(int, p);
}
__device__ __forceinline__ float dot2acc(unsigned int e, unsigned int s, float acc) {
    return __builtin_amdgcn_fdot2(__builtin_bit_cast(h2, e),
                                  __builtin_bit_cast(h2, s), acc, false);
}

template <int CTRL>
__device__ __forceinline__ float dpp_mov_self(float x) {
    return __int_as_float(__builtin_amdgcn_update_dpp(
        __float_as_int(x), __float_as_int(x), CTRL, 0xF, 0xF, false));
}
template <int CTRL>
__device__ __forceinline__ float dpp_mov_zero(float x) {
    return __int_as_float(__builtin_amdgcn_update_dpp(
        0, __float_as_int(x), CTRL, 0xF, 0xF, true));
}
__device__ __forceinline__ float wave_max_bcast(float x) {
    x = fmaxf(x, dpp_mov_self<0x111>(x));
    x = fmaxf(x, dpp_mov_self<0x112>(x));
    x = fmaxf(x, dpp_mov_self<0x114>(x));
    x = fmaxf(x, dpp_mov_self<0x118>(x));
    x = fmaxf(x, dpp_mov_self<0x142>(x));
    x = fmaxf(x, dpp_mov_self<0x143>(x));
    return __int_as_float(__builtin_amdgcn_readlane(__float_as_int(x), 63));
}
__device__ __forceinline__ float wave_sum_bcast(float x) {
    x += dpp_mov_zero<0x111>(x);
    x += dpp_mov_zero<0x112>(x);
    x += dpp_mov_zero<0x114>(x);
    x += dpp_mov_zero<0x118>(x);
    x += dpp_mov_zero<0x142>(x);
    x += dpp_mov_zero<0x143>(x);
    return __int_as_float(__builtin_amdgcn_readlane(__float_as_int(x), 63));
}

// ---------------- single merged prep kernel: 127 blocks x 256 ----------------
__global__ __launch_bounds__(256) void prep(const float* __restrict__ uT,
                                            const float* __restrict__ u1,
                                            const float* __restrict__ x,
                                            const float* __restrict__ lg,
                                            float* __restrict__ ws,
                                            float* __restrict__ out) {
    __shared__ float Zl[A_];
    const int t = blockIdx.x, tid = threadIdx.x;
    const int wave = tid >> 6, lane = tid & 63;
    const float* u = uT + (size_t)t * A_ * A_;

    // Z[k] = lse_j u[k][j], wave-parallel per row
    for (int rr = 0; rr < 32; rr++) {
        int r = wave * 32 + rr;
        float a = u[r * A_ + lane];
        float c = u[r * A_ + lane + 64];
        float mx = wave_max_bcast(fmaxf(a, c));
        float s = wave_sum_bcast(__expf(a - mx) + __expf(c - mx));
        if (lane == 0) Zl[r] = mx + __logf(s);
    }
    __syncthreads();

    // E16 store, coalesced in the fwd-consumption layout:
    // addr_u(t,q,h,w,jl,c) = t*8192 + q*1024 + h*512 + w*128 + jl*4 + c
    // uint = pack(e(2i,j), e(2i+1,j)), i = 32h+4q+c, j = 32w+jl
    unsigned int* Et = (unsigned int*)ws + (size_t)t * 8192;
    for (int it = 0; it < 32; it++) {
        int a = it * 256 + tid;     // 0..8191
        int c = a & 3, jl = (a >> 2) & 31, w = (a >> 7) & 3;
        int h = (a >> 9) & 1, q = (a >> 10) & 7;
        int j = 32 * w + jl;
        int i = 32 * h + 4 * q + c;
        float e0 = __expf(u[(2 * i) * A_ + j] - Zl[2 * i]);
        float e1 = __expf(u[(2 * i + 1) * A_ + j] - Zl[2 * i + 1]);
        Et[a] = (unsigned int)packrtz(e0, e1);
    }

    // BC[b][t][j] = bern(x[b][t+1], j)
    {
        int j = tid & 127, hb = tid >> 7;
        float lv = lg[(t + 1) * A_ + j];
        float sp = (lv > 0.f) ? (lv + log1pf(__expf(-lv))) : log1pf(__expf(lv));
        float g0 = -sp, g1 = lv - sp;
        float* BC = ws + BC_OFF;
        for (int b = hb * 32; b < hb * 32 + 32; b++) {
            float xv = x[b * D_ + t + 1];
            BC[((size_t)b * T_ + t) * A_ + j] = (xv != 0.f) ? g1 : g0;
        }
    }

    // block 0, wave 0: log_softmax(u1) -> LP + output 1
    if (t == 0 && wave == 0) {
        float a = u1[lane], c = u1[lane + 64];
        float mx = wave_max_bcast(fmaxf(a, c));
        float s = wave_sum_bcast(__expf(a - mx) + __expf(c - mx));
        float lse = mx + __logf(s);
        ws[LP_OFF + lane] = a - lse;
        ws[LP_OFF + lane + 64] = c - lse;
        out[B_ * A_ + lane] = a - lse;
        out[B_ * A_ + lane + 64] = c - lse;
    }
}

// ---------------- main: 64 blocks x 256 (4 waves), raw barriers ----------------
// RAW barrier: lgkmcnt drain only (LDS visibility); vmcnt loads stay in flight.
#define BARRIER() asm volatile("s_waitcnt lgkmcnt(0)\n\ts_barrier" ::: "memory")

#define STEP(T, EC, EP, BCC, BCP, DOPF)                                       \
    {                                                                         \
        const int p = (T) & 1, np = p ^ 1;                                    \
        if (DOPF) { /* prefetch step T+2 into free buffer EP */               \
            const uint4* pf = (const uint4*)(Eb + (size_t)((T) + 2) * 32768); \
            _Pragma("unroll") for (int q = 0; q < 8; q++) EP[q] = pf[q * 256];\
            BCP = BCg[((T) + 2) * A_];                                       \
            __builtin_amdgcn_sched_barrier(0); /* pin loads here (no sink) */ \
        }                                                                     \
        float4 vm4 = *(const float4*)&vmaxl[p][0];                            \
        const uint4* ewp = (const uint4*)&ewl[p][0] + h * 8;                  \
        uint4 ew_[8];                                                         \
        _Pragma("unroll") for (int q = 0; q < 8; q++) ew_[q] = ewp[q];        \
        float vA = h ? vm4.z : vm4.x;                                         \
        float vB = h ? vm4.w : vm4.y;                                         \
        float m = fmaxf(fmaxf(vm4.x, vm4.y), fmaxf(vm4.z, vm4.w));            \
        float fA = __expf(vA - m), fB = __expf(vB - m);                       \
        float s0 = 0, s1 = 0, s2 = 0, s3 = 0;                                 \
        float r0 = 0, r1 = 0, r2 = 0, r3 = 0;                                 \
        _Pragma("unroll") for (int q = 0; q < 4; q++) {                       \
            s0 = dot2acc(EC[q].x, ew_[q].x, s0);                              \
            s1 = dot2acc(EC[q].y, ew_[q].y, s1);                              \
            s2 = dot2acc(EC[q].z, ew_[q].z, s2);                              \
            s3 = dot2acc(EC[q].w, ew_[q].w, s3);                              \
        }                                                                     \
        _Pragma("unroll") for (int q = 4; q < 8; q++) {                       \
            r0 = dot2acc(EC[q].x, ew_[q].x, r0);                              \
            r1 = dot2acc(EC[q].y, ew_[q].y, r1);                              \
            r2 = dot2acc(EC[q].z, ew_[q].z, r2);                              \
            r3 = dot2acc(EC[q].w, ew_[q].w, r3);                              \
        }                                                                     \
        float S = ((s0 + s1) + (s2 + s3)) * fA + ((r0 + r1) + (r2 + r3)) * fB;\
        S += __shfl_xor(S, 32, 64);                                           \
        float vnew = __logf(S) + m + BCC;                                     \
        float mw2 = wave_max_bcast(vnew);                                     \
        ewl[np][j] = (_Float16)__expf(vnew - mw2);                            \
        vmaxl[np][w] = mw2;                                                   \
        v = vnew;                                                             \
        BARRIER();                                                            \
    }

__global__ __launch_bounds__(256, 1) void fwd(const float* __restrict__ x,
                                              const float* __restrict__ lg,
                                              const float* __restrict__ ws,
                                              float* __restrict__ out) {
    __shared__ __align__(16) _Float16 ewl[2][A_];
    __shared__ __align__(16) float vmaxl[2][4];
    __shared__ float sums[4];
    const int b = blockIdx.x, tid = threadIdx.x;
    const int w = tid >> 6, lane = tid & 63;
    const int h = lane >> 5, jl = lane & 31;
    const int j = 32 * w + jl;

    const char* Eb = (const char*)ws + (size_t)h * 2048 + w * 512 + jl * 16;
    const float* BCg = ws + BC_OFF + (size_t)b * T_ * A_ + j; // + t*A_
    const float* LP = ws + LP_OFF;

    // init v_0[j] = log_p_a1[j] + bern(x[b][0], j)
    float ll = lg[j];
    float sp = (ll > 0.f) ? (ll + log1pf(__expf(-ll))) : log1pf(__expf(ll));
    float xv0 = x[b * D_];
    float v = LP[j] + ((xv0 != 0.f) ? (ll - sp) : (-sp));
    float mw = wave_max_bcast(v);
    ewl[0][j] = (_Float16)__expf(v - mw);
    vmaxl[0][w] = mw;

    uint4 E0[8], E1[8], E2[8];
    float bc0, bc1, bc2;
    {   // preload t=0 -> E0, t=1 -> E1 (E2 filled by step 0's prefetch)
        const uint4* p0 = (const uint4*)(Eb);
        const uint4* p1 = (const uint4*)(Eb + 32768);
#pragma unroll
        for (int q = 0; q < 8; q++) { E0[q] = p0[q * 256]; E1[q] = p1[q * 256]; }
        bc0 = BCg[0];
        bc1 = BCg[A_];
        __builtin_amdgcn_sched_barrier(0);
    }
    bc2 = 0.f;
    BARRIER();

    for (int t = 0; t < 123; t += 3) {  // steps 0..122
        STEP(t + 0, E0, E2, bc0, bc2, 1)
        STEP(t + 1, E1, E0, bc1, bc0, 1)
        STEP(t + 2, E2, E1, bc2, bc1, 1)
    }
    STEP(123, E0, E2, bc0, bc2, 1)  // pf 125 -> E2
    STEP(124, E1, E0, bc1, bc0, 1)  // pf 126 -> E0
    STEP(125, E2, E1, bc2, bc1, 0)
    STEP(126, E0, E1, bc0, bc1, 0)

    // final: L = lse_j v_127[j]
    float4 vmf = *(const float4*)&vmaxl[1][0];
    float mf = fmaxf(fmaxf(vmf.x, vmf.y), fmaxf(vmf.z, vmf.w));
    float sw = wave_sum_bcast(__expf(v - mf)) * 0.5f; // halves duplicate j
    sums[w] = sw;
    BARRIER();
    float tot = (sums[0] + sums[1]) + (sums[2] + sums[3]);
    float L = mf + __logf(tot);
    if (tid < A_) out[b * A_ + tid] = L;
}

extern "C" void kernel_launch(void* const* d_in, const int* in_sizes, int n_in,
                              void* d_out, int out_size, void* d_ws, size_t ws_size,
                              hipStream_t stream) {
    const float* x = (const float*)d_in[0];    // [B,D]
    const float* u1 = (const float*)d_in[1];   // [1,1,1,A]
    const float* uT = (const float*)d_in[2];   // [D-1,A,A]
    const float* lg = (const float*)d_in[3];   // [1,D,1,A]
    float* ws = (float*)d_ws;                  // ~8.32 MB
    float* out = (float*)d_out;

    prep<<<dim3(T_), dim3(256), 0, stream>>>(uT, u1, x, lg, ws, out);
    fwd<<<dim3(B_), dim3(256), 0, stream>>>(x, lg, ws, out);
}